// Round 11
// baseline (75833.856 us; speedup 1.0000x reference)
//
#include <hip/hip_runtime.h>
#include <hip/hip_bf16.h>
#include <cstdint>

#define SENTW 0x7F7F7F7Fu   // float ~3.39e38; |h|<1 never produces it
typedef unsigned long long u64;

// fast activations: v_exp_f32 (2^x) + v_rcp_f32, ~1-2 ulp each
__device__ __forceinline__ float fexp(float x){
  return __builtin_amdgcn_exp2f(x * 1.44269504088896341f);
}
__device__ __forceinline__ float sigf(float x){
  return __builtin_amdgcn_rcpf(1.f + fexp(-x));
}
__device__ __forceinline__ float tanh_fast(float x){
  return 1.f - 2.f*__builtin_amdgcn_rcpf(fexp(2.f*x) + 1.f);
}
__device__ __forceinline__ int good64(u64 v){
  return (int)(((unsigned)v != SENTW) & ((unsigned)(v>>32) != SENTW));
}

// ---------------- embedding ----------------
__global__ __launch_bounds__(256) void k_embed(
    const int* __restrict__ x, const int* __restrict__ xp,
    const float* __restrict__ we, const float* __restrict__ pe,
    float* __restrict__ X)
{
  const int s = blockIdx.x, t = threadIdx.x;
  float4* xr = (float4*)(X + (size_t)s*1024);
  if (t < 224){
    const float4* wr = (const float4*)(we + (size_t)x[s]*896);
    xr[t] = wr[t];
  } else {
    const float4* pr = (const float4*)(pe + (size_t)xp[s]*128);
    xr[t] = pr[t-224];
  }
}

// ---------------- fp32 GEMM: C = A * B^T + bias + (*cadd) ----------------
__global__ __launch_bounds__(256,2) void k_gemm_abT(
    const float* __restrict__ A, const float* __restrict__ B, float* __restrict__ C,
    int M, int N, int K,
    const float* __restrict__ bias, const float* __restrict__ cadd)
{
  __shared__ float As[16][132];
  __shared__ float Bs[16][132];
  const int tid = threadIdx.x;
  const int m0 = blockIdx.y*128, n0 = blockIdx.x*128;
  const int r  = tid>>1, cq = tid&1;
  const int ty = tid>>4, tx = tid&15;

  float acc[8][8];
  #pragma unroll
  for (int i=0;i<8;i++)
    #pragma unroll
    for (int j=0;j<8;j++) acc[i][j]=0.f;

  for (int k0=0;k0<K;k0+=16){
    const float* ap = A + (size_t)(m0+r)*K + k0 + cq*8;
    const float* bp = B + (size_t)(n0+r)*K + k0 + cq*8;
    float4 a0 = *(const float4*)ap;
    float4 a1 = *(const float4*)(ap+4);
    float4 b0 = *(const float4*)bp;
    float4 b1 = *(const float4*)(bp+4);
    __syncthreads();
    As[cq*8+0][r]=a0.x; As[cq*8+1][r]=a0.y; As[cq*8+2][r]=a0.z; As[cq*8+3][r]=a0.w;
    As[cq*8+4][r]=a1.x; As[cq*8+5][r]=a1.y; As[cq*8+6][r]=a1.z; As[cq*8+7][r]=a1.w;
    Bs[cq*8+0][r]=b0.x; Bs[cq*8+1][r]=b0.y; Bs[cq*8+2][r]=b0.z; Bs[cq*8+3][r]=b0.w;
    Bs[cq*8+4][r]=b1.x; Bs[cq*8+5][r]=b1.y; Bs[cq*8+6][r]=b1.z; Bs[cq*8+7][r]=b1.w;
    __syncthreads();
    #pragma unroll
    for (int k=0;k<16;k++){
      float4 av0 = *(const float4*)&As[k][ty*8];
      float4 av1 = *(const float4*)&As[k][ty*8+4];
      float4 bv0 = *(const float4*)&Bs[k][tx*8];
      float4 bv1 = *(const float4*)&Bs[k][tx*8+4];
      float a[8]={av0.x,av0.y,av0.z,av0.w,av1.x,av1.y,av1.z,av1.w};
      float b[8]={bv0.x,bv0.y,bv0.z,bv0.w,bv1.x,bv1.y,bv1.z,bv1.w};
      #pragma unroll
      for (int i=0;i<8;i++)
        #pragma unroll
        for (int j=0;j<8;j++)
          acc[i][j] = fmaf(a[i],b[j],acc[i][j]);
    }
  }

  float cb = cadd ? *cadd : 0.f;
  float bv[8];
  if (bias){
    float4 t0 = *(const float4*)&bias[n0+tx*8];
    float4 t1 = *(const float4*)&bias[n0+tx*8+4];
    bv[0]=t0.x; bv[1]=t0.y; bv[2]=t0.z; bv[3]=t0.w;
    bv[4]=t1.x; bv[5]=t1.y; bv[6]=t1.z; bv[7]=t1.w;
  } else {
    #pragma unroll
    for (int j=0;j<8;j++) bv[j]=0.f;
  }
  #pragma unroll
  for (int i=0;i<8;i++){
    float* cp = C + (size_t)(m0+ty*8+i)*N + n0+tx*8;
    float4 o0, o1;
    o0.x=acc[i][0]+bv[0]+cb; o0.y=acc[i][1]+bv[1]+cb;
    o0.z=acc[i][2]+bv[2]+cb; o0.w=acc[i][3]+bv[3]+cb;
    o1.x=acc[i][4]+bv[4]+cb; o1.y=acc[i][5]+bv[5]+cb;
    o1.z=acc[i][6]+bv[6]+cb; o1.w=acc[i][7]+bv[7]+cb;
    *(float4*)cp = o0; *(float4*)(cp+4) = o1;
  }
}

// ---- merged head/dep GEMM ----
__global__ __launch_bounds__(256,2) void k_gemm_hd(
    const float* __restrict__ A,
    const float* __restrict__ Wh, const float* __restrict__ bh, float* __restrict__ Chead,
    const float* __restrict__ Wd, const float* __restrict__ bd, float* __restrict__ Cdep)
{
  __shared__ float As[16][132];
  __shared__ float Bs[16][132];
  const int tid = threadIdx.x;
  const int m0 = blockIdx.y*128;
  const int half = blockIdx.x >> 3;
  const int n0 = (blockIdx.x & 7)*128;
  const float* B    = half ? Wd : Wh;
  const float* bias = half ? bd : bh;
  float*       C    = half ? Cdep : Chead;
  const int r  = tid>>1, cq = tid&1;
  const int ty = tid>>4, tx = tid&15;

  float acc[8][8];
  #pragma unroll
  for (int i=0;i<8;i++)
    #pragma unroll
    for (int j=0;j<8;j++) acc[i][j]=0.f;

  for (int k0=0;k0<1024;k0+=16){
    const float* ap = A + (size_t)(m0+r)*1024 + k0 + cq*8;
    const float* bp = B + (size_t)(n0+r)*1024 + k0 + cq*8;
    float4 a0 = *(const float4*)ap;
    float4 a1 = *(const float4*)(ap+4);
    float4 b0 = *(const float4*)bp;
    float4 b1 = *(const float4*)(bp+4);
    __syncthreads();
    As[cq*8+0][r]=a0.x; As[cq*8+1][r]=a0.y; As[cq*8+2][r]=a0.z; As[cq*8+3][r]=a0.w;
    As[cq*8+4][r]=a1.x; As[cq*8+5][r]=a1.y; As[cq*8+6][r]=a1.z; As[cq*8+7][r]=a1.w;
    Bs[cq*8+0][r]=b0.x; Bs[cq*8+1][r]=b0.y; Bs[cq*8+2][r]=b0.z; Bs[cq*8+3][r]=b0.w;
    Bs[cq*8+4][r]=b1.x; Bs[cq*8+5][r]=b1.y; Bs[cq*8+6][r]=b1.z; Bs[cq*8+7][r]=b1.w;
    __syncthreads();
    #pragma unroll
    for (int k=0;k<16;k++){
      float4 av0 = *(const float4*)&As[k][ty*8];
      float4 av1 = *(const float4*)&As[k][ty*8+4];
      float4 bv0 = *(const float4*)&Bs[k][tx*8];
      float4 bv1 = *(const float4*)&Bs[k][tx*8+4];
      float a[8]={av0.x,av0.y,av0.z,av0.w,av1.x,av1.y,av1.z,av1.w};
      float b[8]={bv0.x,bv0.y,bv0.z,bv0.w,bv1.x,bv1.y,bv1.z,bv1.w};
      #pragma unroll
      for (int i=0;i<8;i++)
        #pragma unroll
        for (int j=0;j<8;j++)
          acc[i][j] = fmaf(a[i],b[j],acc[i][j]);
    }
  }

  float4 t0 = *(const float4*)&bias[n0+tx*8];
  float4 t1 = *(const float4*)&bias[n0+tx*8+4];
  float bv[8] = {t0.x,t0.y,t0.z,t0.w,t1.x,t1.y,t1.z,t1.w};
  #pragma unroll
  for (int i=0;i<8;i++){
    float* cp = C + (size_t)(m0+ty*8+i)*1024 + n0+tx*8;
    float4 o0, o1;
    o0.x=acc[i][0]+bv[0]; o0.y=acc[i][1]+bv[1];
    o0.z=acc[i][2]+bv[2]; o0.w=acc[i][3]+bv[3];
    o1.x=acc[i][4]+bv[4]; o1.y=acc[i][5]+bv[5];
    o1.z=acc[i][6]+bv[6]; o1.w=acc[i][7]+bv[7];
    *(float4*)cp = o0; *(float4*)(cp+4) = o1;
  }
}

// ---------------- LSTM scan: XCD-local exchange + LLC mirror ----------------
// Launch 1024 WGs x 512 thr. Election: each WG reads HW_REG_XCC_ID, claims a
// per-XCD rank; first two XCDs with a rank-0 WG own fwd/bwd; ranks 0..31 on
// an owner XCD participate (logical WG id = rank), all others exit. Work and
// output are identical regardless of physical placement (deterministic).
// Exchange per step: producer wave lane0 plain-stores its 2-unit u64 to exA
// (write-back -> dirty in the direction's SHARED per-XCD L2) and sc0+sc1
// mirror-stores to exB (LLC, authoritative). Consumers (tid<256) sc0-poll
// their private exA slot (L1-bypass -> shared L2: RTT ~100-200ns); per-thread
// sticky aOk discovered at t<=2 decides fast vs mirror path, so a broken fast
// path degrades to the R5-proven LLC exchange (no hang, no corruption).
__global__ __launch_bounds__(512,1) void k_lstm_scan(
    const float* __restrict__ pre,   // [1024][4096]: dir*2048 + gate*512 + unit
    const float* __restrict__ Whh,   // [2][2048][512] (this layer)
    float* __restrict__ out,         // [1024][1024]; fwd 0..511, bwd 512..1023
    u64* __restrict__ exA,           // [2][1024][256] fast exchange (ws, sentinel-init)
    u64* __restrict__ exB,           // [2][1024][256] LLC mirror (sentinel-init)
    unsigned* __restrict__ ctrl)     // [0]=dirCnt [1],[2]=owner xcc+1 [8+x]=roster
{
  const int tid = threadIdx.x;
  __shared__ int sh_dir, sh_w;
  if (tid == 0){
    unsigned xcc;
    asm volatile("s_getreg_b32 %0, hwreg(HW_REG_XCC_ID)" : "=s"(xcc));
    xcc &= 7u;
    unsigned r = __hip_atomic_fetch_add(ctrl+8+xcc, 1u, __ATOMIC_RELAXED, __HIP_MEMORY_SCOPE_AGENT);
    if (r == 0u){
      unsigned d = __hip_atomic_fetch_add(ctrl+0, 1u, __ATOMIC_RELAXED, __HIP_MEMORY_SCOPE_AGENT);
      if (d < 2u)
        __hip_atomic_store(ctrl+1+d, xcc+1u, __ATOMIC_RELAXED, __HIP_MEMORY_SCOPE_AGENT);
    }
    unsigned o0, o1;
    do {
      o0 = __hip_atomic_load(ctrl+1, __ATOMIC_RELAXED, __HIP_MEMORY_SCOPE_AGENT);
      o1 = __hip_atomic_load(ctrl+2, __ATOMIC_RELAXED, __HIP_MEMORY_SCOPE_AGENT);
    } while (o0 == 0u || o1 == 0u);
    int dir = (o0 == xcc+1u) ? 0 : (o1 == xcc+1u) ? 1 : -1;
    sh_dir = (dir >= 0 && r < 32u) ? dir : -1;
    sh_w   = (int)r;
  }
  __syncthreads();
  const int dir = sh_dir;
  const int w   = sh_w;
  if (dir < 0) return;

  const int kc  = tid & 7;          // k-chunk (64 floats)
  const int rl  = tid >> 3;         // local row 0..63
  const int gate= rl & 3;           // i,f,g,o
  const int ul  = rl >> 2;          // local unit 0..15
  const int unit= w*16 + ul;
  const int grow= gate*512 + unit;
  const int wv  = tid >> 6;         // wave 0..7
  const int lane= tid & 63;

  __shared__ float hsh[2][544];     // swizzled, conflict-free (R2-verified)
  const int wslot = (tid>>5)*68 + ((2*tid)&63);

  float wreg[64];
  {
    const float* wp = Whh + ((size_t)dir*2048 + grow)*512 + kc*64;
    #pragma unroll
    for (int j=0;j<16;j++){
      float4 q = *(const float4*)(wp + 4*j);
      wreg[4*j+0]=q.x; wreg[4*j+1]=q.y; wreg[4*j+2]=q.z; wreg[4*j+3]=q.w;
    }
  }

  const float* prebase = pre + (size_t)dir*2048 + grow;
  float c = 0.f;
  const int base = tid & 32;
  int aOk = 0;

  for (int t=0;t<1024;t++){
    const int s = dir ? (1023 - t) : t;

    float preval = 0.f;
    if (kc==0) preval = prebase[(size_t)s*4096];

    float accv = 0.f;
    if (t > 0){
      if (tid < 256){
        const int sp = dir ? (s + 1) : (s - 1);
        u64* fa = exA + ((size_t)(dir<<10) + sp)*256 + tid;
        u64* fb = exB + ((size_t)(dir<<10) + sp)*256 + tid;
        u64 vv;
        if (t <= 2){
          // discovery: poll both paths; note whether fast path delivers
          for(;;){
            u64 va, vb;
            asm volatile(
              "global_load_dwordx2 %0, %2, off sc0\n\t"
              "global_load_dwordx2 %1, %3, off sc0 sc1\n\t"
              "s_waitcnt vmcnt(0)"
              : "=&v"(va), "=&v"(vb) : "v"(fa), "v"(fb) : "memory");
            if (good64(va)){ vv = va; aOk = 1; break; }
            if (good64(vb)){ vv = vb; break; }
          }
        } else if (aOk){
          int n = 0;
          for(;;){
            u64 va;
            asm volatile("global_load_dwordx2 %0, %1, off sc0\n\ts_waitcnt vmcnt(0)"
                         : "=v"(va) : "v"(fa) : "memory");
            if (good64(va)){ vv = va; break; }
            if ((++n & 255) == 0){          // safety valve: authoritative mirror
              u64 vb;
              asm volatile("global_load_dwordx2 %0, %1, off sc0 sc1\n\ts_waitcnt vmcnt(0)"
                           : "=v"(vb) : "v"(fb) : "memory");
              if (good64(vb)){ vv = vb; break; }
            }
          }
        } else {
          for(;;){                           // R5-proven LLC path
            u64 vb;
            asm volatile("global_load_dwordx2 %0, %1, off sc0 sc1\n\ts_waitcnt vmcnt(0)"
                         : "=v"(vb) : "v"(fb) : "memory");
            if (good64(vb)){ vv = vb; break; }
          }
        }
        float* hb = hsh[t & 1];
        hb[wslot]   = __uint_as_float((unsigned)vv);
        hb[wslot+1] = __uint_as_float((unsigned)(vv>>32));
      }
      __syncthreads();

      const float* hv = hsh[t & 1] + kc*68;
      float p0=0.f,p1=0.f,p2=0.f,p3=0.f;
      #pragma unroll
      for (int j=0;j<16;j++){
        float4 q = *(const float4*)(hv + 4*j);
        p0 = fmaf(wreg[4*j+0], q.x, p0);
        p1 = fmaf(wreg[4*j+1], q.y, p1);
        p2 = fmaf(wreg[4*j+2], q.z, p2);
        p3 = fmaf(wreg[4*j+3], q.w, p3);
      }
      accv = (p0+p1)+(p2+p3);
      accv += __shfl_xor(accv, 1);
      accv += __shfl_xor(accv, 2);
      accv += __shfl_xor(accv, 4);
    }
    float act = 0.f;
    if (kc==0){
      float g = accv + preval;
      act = (gate==2) ? tanh_fast(g) : sigf(g);
    }
    float ai = __shfl(act, base+0);
    float af = __shfl(act, base+8);
    float ag = __shfl(act, base+16);
    float ao = __shfl(act, base+24);
    float h = 0.f;
    if ((lane&31)==0){                // lanes 0,32: units 16w+2wv, 16w+2wv+1
      c = af*c + ai*ag;
      h = ao*tanh_fast(c);
    }
    float hA = __shfl(h, 0);
    float hB = __shfl(h, 32);
    if (lane == 0){
      u64 pv = ((u64)__float_as_uint(hB) << 32) | __float_as_uint(hA);
      u64* pa = exA + ((size_t)(dir<<10) + s)*256 + (w*8 + wv);
      u64* pb = exB + ((size_t)(dir<<10) + s)*256 + (w*8 + wv);
      // plain store -> dirty in this direction's shared L2 (fast path)
      asm volatile("global_store_dwordx2 %0, %1, off" :: "v"(pa), "v"(pv) : "memory");
      // mirror -> LLC (authoritative fallback)
      asm volatile("global_store_dwordx2 %0, %1, off sc0 sc1" :: "v"(pb), "v"(pv) : "memory");
    }
    if ((lane&31)==0){
      out[(size_t)s*1024 + dir*512 + unit] = h;   // plain data store for GEMMs
    }
  }
}

// ---------------- row softmax, in place ----------------
__global__ __launch_bounds__(256) void k_softmax(float* __restrict__ P){
  __shared__ float redm[4], reds[4];
  const int i = blockIdx.x, tid = threadIdx.x;
  float4 v = *(float4*)&P[(size_t)i*1024 + tid*4];
  float m = fmaxf(fmaxf(v.x,v.y), fmaxf(v.z,v.w));
  #pragma unroll
  for (int o=32;o;o>>=1) m = fmaxf(m, __shfl_xor(m,o));
  if ((tid&63)==0) redm[tid>>6] = m;
  __syncthreads();
  m = fmaxf(fmaxf(redm[0],redm[1]), fmaxf(redm[2],redm[3]));
  v.x = expf(v.x-m); v.y = expf(v.y-m); v.z = expf(v.z-m); v.w = expf(v.w-m);
  float su = v.x+v.y+v.z+v.w;
  #pragma unroll
  for (int o=32;o;o>>=1) su += __shfl_xor(su,o);
  if ((tid&63)==0) reds[tid>>6] = su;
  __syncthreads();
  su = reds[0]+reds[1]+reds[2]+reds[3];
  float inv = 1.f/su;
  v.x*=inv; v.y*=inv; v.z*=inv; v.w*=inv;
  *(float4*)&P[(size_t)i*1024 + tid*4] = v;
}

extern "C" void kernel_launch(void* const* d_in, const int* in_sizes, int n_in,
                              void* d_out, int out_size, void* d_ws, size_t ws_size,
                              hipStream_t stream)
{
  const int*   x    = (const int*)d_in[0];
  const int*   xp   = (const int*)d_in[1];
  const float* we   = (const float*)d_in[2];
  const float* pe   = (const float*)d_in[3];
  const float* Wih  = (const float*)d_in[4];
  const float* Whh  = (const float*)d_in[5];
  const float* bl   = (const float*)d_in[6];
  const float* Wh   = (const float*)d_in[7];
  const float* bh   = (const float*)d_in[8];
  const float* Wd   = (const float*)d_in[9];
  const float* bd   = (const float*)d_in[10];
  const float* Wbi  = (const float*)d_in[11];
  const float* bbi  = (const float*)d_in[12];
  float* outp = (float*)d_out;

  char* ws = (char*)d_ws;
  float* X0   = (float*)(ws);                    // [0,4M)  embeddings (dead after pre-GEMM0)
  float* pre  = (float*)(ws + ((size_t)4<<20));  // [4M,20M)
  float* out0 = (float*)(ws + ((size_t)20<<20)); // [20M,24M)
  float* out1 = (float*)(ws + ((size_t)24<<20)); // [24M,28M)
  float* head = (float*)(ws);                    // reuse [0,4M) after scans
  float* dep  = (float*)(ws + ((size_t)4<<20));  // reuse [4M,8M)
  float* Ubuf = (float*)(ws + ((size_t)8<<20));  // reuse [8M,12M)

  u64*      exA   = (u64*)ws;                           // [0,4M): fast exchange (after X0 dies)
  u64*      exB   = (u64*)d_out;                        // 4MB LLC mirror (d_out dead until final GEMM)
  unsigned* ctrl0 = (unsigned*)(ws + ((size_t)24<<20)); // inside out1 (dead until scan1)
  unsigned* ctrl1 = (unsigned*)(ws + ((size_t)20<<20)); // inside out0 (dead after pre-GEMM1)

  dim3 blk(256);

  hipMemsetAsync(exB, 0x7F, (size_t)4<<20, stream);     // mirror sentinel for scan0
  k_embed<<<1024, blk, 0, stream>>>(x, xp, we, pe, X0);

  k_gemm_abT<<<dim3(32,8), blk, 0, stream>>>(X0, Wih, pre, 1024, 4096, 1024, bl, nullptr);
  hipMemsetAsync(exA, 0x7F, (size_t)4<<20, stream);     // X0 dead now
  hipMemsetAsync(ctrl0, 0, 64, stream);
  k_lstm_scan<<<1024, dim3(512), 0, stream>>>(pre, Whh, out0, exA, exB, ctrl0);

  k_gemm_abT<<<dim3(32,8), blk, 0, stream>>>(out0, Wih + (size_t)4096*1024, pre,
                                             1024, 4096, 1024, bl + 4096, nullptr);
  hipMemsetAsync(exA, 0x7F, (size_t)4<<20, stream);
  hipMemsetAsync(exB, 0x7F, (size_t)4<<20, stream);
  hipMemsetAsync(ctrl1, 0, 64, stream);                 // out0 consumed by pre-GEMM1 already
  k_lstm_scan<<<1024, dim3(512), 0, stream>>>(pre, Whh + (size_t)2*2048*512, out1, exA, exB, ctrl1);

  k_gemm_hd <<<dim3(16,8), blk, 0, stream>>>(out1, Wh, bh, head, Wd, bd, dep);
  k_gemm_abT<<<dim3(8,8), blk, 0, stream>>>(dep,  Wbi, Ubuf, 1024, 1024, 1024, nullptr, nullptr);
  k_gemm_abT<<<dim3(8,8), blk, 0, stream>>>(head, Ubuf, outp, 1024, 1024, 1024, nullptr, bbi);

  k_softmax<<<1024, blk, 0, stream>>>(outp);
}

// Round 12
// 6721.213 us; speedup vs baseline: 11.2828x; 11.2828x over previous
//
#include <hip/hip_runtime.h>
#include <hip/hip_bf16.h>
#include <cstdint>

#define SENTW 0x7F7F7F7Fu   // float ~3.39e38; |h|<1 never produces it

typedef unsigned uint4v __attribute__((ext_vector_type(4)));

// fast activations: v_exp_f32 (2^x) + v_rcp_f32, ~1-2 ulp each
__device__ __forceinline__ float fexp(float x){
  return __builtin_amdgcn_exp2f(x * 1.44269504088896341f);
}
__device__ __forceinline__ float sigf(float x){
  return __builtin_amdgcn_rcpf(1.f + fexp(-x));
}
__device__ __forceinline__ float tanh_fast(float x){
  return 1.f - 2.f*__builtin_amdgcn_rcpf(fexp(2.f*x) + 1.f);
}

// ---------------- fp32 GEMM: C = A * B^T + bias + (*cadd) ----------------
// 128x128 tile, BK=16, 256 thr, 8x8 micro-tile. Register-prefetch pipeline:
// next K-tile's global loads issue before the compute loop (latency hides
// under FMAs instead of stalling at the LDS-write barrier).
__global__ __launch_bounds__(256,2) void k_gemm_abT(
    const float* __restrict__ A, const float* __restrict__ B, float* __restrict__ C,
    int M, int N, int K,
    const float* __restrict__ bias, const float* __restrict__ cadd)
{
  __shared__ float As[16][132];
  __shared__ float Bs[16][132];
  const int tid = threadIdx.x;
  const int m0 = blockIdx.y*128, n0 = blockIdx.x*128;
  const int r  = tid>>1, cq = tid&1;
  const int ty = tid>>4, tx = tid&15;

  float acc[8][8];
  #pragma unroll
  for (int i=0;i<8;i++)
    #pragma unroll
    for (int j=0;j<8;j++) acc[i][j]=0.f;

  const float* ap = A + (size_t)(m0+r)*K + cq*8;
  const float* bp = B + (size_t)(n0+r)*K + cq*8;
  float4 a0 = *(const float4*)(ap);
  float4 a1 = *(const float4*)(ap+4);
  float4 b0 = *(const float4*)(bp);
  float4 b1 = *(const float4*)(bp+4);

  for (int k0=0;k0<K;k0+=16){
    __syncthreads();   // prior compute finished reading LDS
    As[cq*8+0][r]=a0.x; As[cq*8+1][r]=a0.y; As[cq*8+2][r]=a0.z; As[cq*8+3][r]=a0.w;
    As[cq*8+4][r]=a1.x; As[cq*8+5][r]=a1.y; As[cq*8+6][r]=a1.z; As[cq*8+7][r]=a1.w;
    Bs[cq*8+0][r]=b0.x; Bs[cq*8+1][r]=b0.y; Bs[cq*8+2][r]=b0.z; Bs[cq*8+3][r]=b0.w;
    Bs[cq*8+4][r]=b1.x; Bs[cq*8+5][r]=b1.y; Bs[cq*8+6][r]=b1.z; Bs[cq*8+7][r]=b1.w;
    __syncthreads();
    if (k0+16 < K){    // prefetch next tile into regs; latency hides under compute
      a0 = *(const float4*)(ap+k0+16);
      a1 = *(const float4*)(ap+k0+20);
      b0 = *(const float4*)(bp+k0+16);
      b1 = *(const float4*)(bp+k0+20);
    }
    #pragma unroll
    for (int k=0;k<16;k++){
      float4 av0 = *(const float4*)&As[k][ty*8];
      float4 av1 = *(const float4*)&As[k][ty*8+4];
      float4 bv0 = *(const float4*)&Bs[k][tx*8];
      float4 bv1 = *(const float4*)&Bs[k][tx*8+4];
      float a[8]={av0.x,av0.y,av0.z,av0.w,av1.x,av1.y,av1.z,av1.w};
      float b[8]={bv0.x,bv0.y,bv0.z,bv0.w,bv1.x,bv1.y,bv1.z,bv1.w};
      #pragma unroll
      for (int i=0;i<8;i++)
        #pragma unroll
        for (int j=0;j<8;j++)
          acc[i][j] = fmaf(a[i],b[j],acc[i][j]);
    }
  }

  float cb = cadd ? *cadd : 0.f;
  float bv[8];
  if (bias){
    float4 t0 = *(const float4*)&bias[n0+tx*8];
    float4 t1 = *(const float4*)&bias[n0+tx*8+4];
    bv[0]=t0.x; bv[1]=t0.y; bv[2]=t0.z; bv[3]=t0.w;
    bv[4]=t1.x; bv[5]=t1.y; bv[6]=t1.z; bv[7]=t1.w;
  } else {
    #pragma unroll
    for (int j=0;j<8;j++) bv[j]=0.f;
  }
  #pragma unroll
  for (int i=0;i<8;i++){
    float* cp = C + (size_t)(m0+ty*8+i)*N + n0+tx*8;
    float4 o0, o1;
    o0.x=acc[i][0]+bv[0]+cb; o0.y=acc[i][1]+bv[1]+cb;
    o0.z=acc[i][2]+bv[2]+cb; o0.w=acc[i][3]+bv[3]+cb;
    o1.x=acc[i][4]+bv[4]+cb; o1.y=acc[i][5]+bv[5]+cb;
    o1.z=acc[i][6]+bv[6]+cb; o1.w=acc[i][7]+bv[7]+cb;
    *(float4*)cp = o0; *(float4*)(cp+4) = o1;
  }
}

// ---- fused embed + pre-GEMM0: A row m = concat(we[x[m]], pe[xp[m]]) ----
// Same tile/pipeline as k_gemm_abT; A is gathered (no X0 materialization).
// 8-float segments never straddle the 896 boundary (896 % 16 == 0).
__global__ __launch_bounds__(256,2) void k_gemm_emb(
    const int* __restrict__ x, const int* __restrict__ xp,
    const float* __restrict__ we, const float* __restrict__ pe,
    const float* __restrict__ B, float* __restrict__ C,
    const float* __restrict__ bias)   // M=1024, N=4096, K=1024
{
  __shared__ float As[16][132];
  __shared__ float Bs[16][132];
  const int tid = threadIdx.x;
  const int m0 = blockIdx.y*128, n0 = blockIdx.x*128;
  const int r  = tid>>1, cq = tid&1;
  const int ty = tid>>4, tx = tid&15;

  float acc[8][8];
  #pragma unroll
  for (int i=0;i<8;i++)
    #pragma unroll
    for (int j=0;j<8;j++) acc[i][j]=0.f;

  const int row = m0 + r;
  const float* bw  = we + (size_t)x[row]*896;         // k in [0,896)
  const float* bpo = pe + (size_t)xp[row]*128 - 896;  // k in [896,1024)
  const float* bp  = B + (size_t)(n0+r)*1024 + cq*8;

  int kk = cq*8;
  const float* asrc = (kk < 896 ? bw : bpo) + kk;
  float4 a0 = *(const float4*)(asrc);
  float4 a1 = *(const float4*)(asrc+4);
  float4 b0 = *(const float4*)(bp);
  float4 b1 = *(const float4*)(bp+4);

  for (int k0=0;k0<1024;k0+=16){
    __syncthreads();
    As[cq*8+0][r]=a0.x; As[cq*8+1][r]=a0.y; As[cq*8+2][r]=a0.z; As[cq*8+3][r]=a0.w;
    As[cq*8+4][r]=a1.x; As[cq*8+5][r]=a1.y; As[cq*8+6][r]=a1.z; As[cq*8+7][r]=a1.w;
    Bs[cq*8+0][r]=b0.x; Bs[cq*8+1][r]=b0.y; Bs[cq*8+2][r]=b0.z; Bs[cq*8+3][r]=b0.w;
    Bs[cq*8+4][r]=b1.x; Bs[cq*8+5][r]=b1.y; Bs[cq*8+6][r]=b1.z; Bs[cq*8+7][r]=b1.w;
    __syncthreads();
    if (k0+16 < 1024){
      kk = k0+16+cq*8;
      asrc = (kk < 896 ? bw : bpo) + kk;
      a0 = *(const float4*)(asrc);
      a1 = *(const float4*)(asrc+4);
      b0 = *(const float4*)(bp+k0+16);
      b1 = *(const float4*)(bp+k0+20);
    }
    #pragma unroll
    for (int k=0;k<16;k++){
      float4 av0 = *(const float4*)&As[k][ty*8];
      float4 av1 = *(const float4*)&As[k][ty*8+4];
      float4 bv0 = *(const float4*)&Bs[k][tx*8];
      float4 bv1 = *(const float4*)&Bs[k][tx*8+4];
      float a[8]={av0.x,av0.y,av0.z,av0.w,av1.x,av1.y,av1.z,av1.w};
      float b[8]={bv0.x,bv0.y,bv0.z,bv0.w,bv1.x,bv1.y,bv1.z,bv1.w};
      #pragma unroll
      for (int i=0;i<8;i++)
        #pragma unroll
        for (int j=0;j<8;j++)
          acc[i][j] = fmaf(a[i],b[j],acc[i][j]);
    }
  }

  float4 t0 = *(const float4*)&bias[n0+tx*8];
  float4 t1 = *(const float4*)&bias[n0+tx*8+4];
  float bv[8] = {t0.x,t0.y,t0.z,t0.w,t1.x,t1.y,t1.z,t1.w};
  #pragma unroll
  for (int i=0;i<8;i++){
    float* cp = C + (size_t)(m0+ty*8+i)*4096 + n0+tx*8;
    float4 o0, o1;
    o0.x=acc[i][0]+bv[0]; o0.y=acc[i][1]+bv[1];
    o0.z=acc[i][2]+bv[2]; o0.w=acc[i][3]+bv[3];
    o1.x=acc[i][4]+bv[4]; o1.y=acc[i][5]+bv[5];
    o1.z=acc[i][6]+bv[6]; o1.w=acc[i][7]+bv[7];
    *(float4*)cp = o0; *(float4*)(cp+4) = o1;
  }
}

// ---- merged head/dep GEMM (same pipeline) ----
__global__ __launch_bounds__(256,2) void k_gemm_hd(
    const float* __restrict__ A,
    const float* __restrict__ Wh, const float* __restrict__ bh, float* __restrict__ Chead,
    const float* __restrict__ Wd, const float* __restrict__ bd, float* __restrict__ Cdep)
{
  __shared__ float As[16][132];
  __shared__ float Bs[16][132];
  const int tid = threadIdx.x;
  const int m0 = blockIdx.y*128;
  const int half = blockIdx.x >> 3;
  const int n0 = (blockIdx.x & 7)*128;
  const float* B    = half ? Wd : Wh;
  const float* bias = half ? bd : bh;
  float*       C    = half ? Cdep : Chead;
  const int r  = tid>>1, cq = tid&1;
  const int ty = tid>>4, tx = tid&15;

  float acc[8][8];
  #pragma unroll
  for (int i=0;i<8;i++)
    #pragma unroll
    for (int j=0;j<8;j++) acc[i][j]=0.f;

  const float* ap = A + (size_t)(m0+r)*1024 + cq*8;
  const float* bp = B + (size_t)(n0+r)*1024 + cq*8;
  float4 a0 = *(const float4*)(ap);
  float4 a1 = *(const float4*)(ap+4);
  float4 b0 = *(const float4*)(bp);
  float4 b1 = *(const float4*)(bp+4);

  for (int k0=0;k0<1024;k0+=16){
    __syncthreads();
    As[cq*8+0][r]=a0.x; As[cq*8+1][r]=a0.y; As[cq*8+2][r]=a0.z; As[cq*8+3][r]=a0.w;
    As[cq*8+4][r]=a1.x; As[cq*8+5][r]=a1.y; As[cq*8+6][r]=a1.z; As[cq*8+7][r]=a1.w;
    Bs[cq*8+0][r]=b0.x; Bs[cq*8+1][r]=b0.y; Bs[cq*8+2][r]=b0.z; Bs[cq*8+3][r]=b0.w;
    Bs[cq*8+4][r]=b1.x; Bs[cq*8+5][r]=b1.y; Bs[cq*8+6][r]=b1.z; Bs[cq*8+7][r]=b1.w;
    __syncthreads();
    if (k0+16 < 1024){
      a0 = *(const float4*)(ap+k0+16);
      a1 = *(const float4*)(ap+k0+20);
      b0 = *(const float4*)(bp+k0+16);
      b1 = *(const float4*)(bp+k0+20);
    }
    #pragma unroll
    for (int k=0;k<16;k++){
      float4 av0 = *(const float4*)&As[k][ty*8];
      float4 av1 = *(const float4*)&As[k][ty*8+4];
      float4 bv0 = *(const float4*)&Bs[k][tx*8];
      float4 bv1 = *(const float4*)&Bs[k][tx*8+4];
      float a[8]={av0.x,av0.y,av0.z,av0.w,av1.x,av1.y,av1.z,av1.w};
      float b[8]={bv0.x,bv0.y,bv0.z,bv0.w,bv1.x,bv1.y,bv1.z,bv1.w};
      #pragma unroll
      for (int i=0;i<8;i++)
        #pragma unroll
        for (int j=0;j<8;j++)
          acc[i][j] = fmaf(a[i],b[j],acc[i][j]);
    }
  }

  float4 t0 = *(const float4*)&bias[n0+tx*8];
  float4 t1 = *(const float4*)&bias[n0+tx*8+4];
  float bv[8] = {t0.x,t0.y,t0.z,t0.w,t1.x,t1.y,t1.z,t1.w};
  #pragma unroll
  for (int i=0;i<8;i++){
    float* cp = C + (size_t)(m0+ty*8+i)*1024 + n0+tx*8;
    float4 o0, o1;
    o0.x=acc[i][0]+bv[0]; o0.y=acc[i][1]+bv[1];
    o0.z=acc[i][2]+bv[2]; o0.w=acc[i][3]+bv[3];
    o1.x=acc[i][4]+bv[4]; o1.y=acc[i][5]+bv[5];
    o1.z=acc[i][6]+bv[6]; o1.w=acc[i][7]+bv[7];
    *(float4*)cp = o0; *(float4*)(cp+4) = o1;
  }
}

// ---------------- LSTM scan (byte-identical to R7 measurement winner) -------
// 64 WGs x 512 thr; 32/dir, 16 units/WG, weights register-resident; sentinel
// data-as-flag sync: wave-0 polls full h via 2x dwordx4 sc0 sc1; swizzled LDS
// redistribute; paired u64 atomic-swap publish. ~2.92 ms measured.
__global__ __launch_bounds__(512,1) void k_lstm_scan(
    const float* __restrict__ pre,   // [1024][4096]: dir*2048 + gate*512 + unit
    const float* __restrict__ Whh,   // [2][2048][512] (this layer)
    float* __restrict__ out)         // [1024][1024]; fwd 0..511, bwd 512..1023
{
  const int wg  = blockIdx.x;
  const int dir = wg >> 5;
  const int w   = wg & 31;
  const int tid = threadIdx.x;
  const int kc  = tid & 7;
  const int rl  = tid >> 3;
  const int gate= rl & 3;
  const int ul  = rl >> 2;
  const int unit= w*16 + ul;
  const int grow= gate*512 + unit;

  __shared__ float hsh[2][544];

  float wreg[64];
  {
    const float* wp = Whh + ((size_t)dir*2048 + grow)*512 + kc*64;
    #pragma unroll
    for (int j=0;j<16;j++){
      float4 q = *(const float4*)(wp + 4*j);
      wreg[4*j+0]=q.x; wreg[4*j+1]=q.y; wreg[4*j+2]=q.z; wreg[4*j+3]=q.w;
    }
  }

  unsigned* ob = (unsigned*)out;
  const float* prebase = pre + (size_t)dir*2048 + grow;
  float c = 0.f;
  const int base = (tid & 32);

  for (int t=0;t<1024;t++){
    const int s  = dir ? (1023 - t) : t;
    const int sp = dir ? (s + 1) : (s - 1);

    float preval = 0.f;
    if (kc==0) preval = prebase[(size_t)s*4096];

    float accv = 0.f;
    if (t > 0){
      if (tid < 64){
        const unsigned* hp = ob + (size_t)sp*1024 + dir*512 + 8*tid;
        uint4v a, b;
        for(;;){
          asm volatile(
            "global_load_dwordx4 %0, %2, off sc0 sc1\n\t"
            "global_load_dwordx4 %1, %3, off sc0 sc1\n\t"
            "s_waitcnt vmcnt(0)"
            : "=&v"(a), "=&v"(b)
            : "v"(hp), "v"(hp+4)
            : "memory");
          unsigned ok = 1u;
          ok &= (unsigned)(a.x!=SENTW) & (unsigned)(a.y!=SENTW);
          ok &= (unsigned)(a.z!=SENTW) & (unsigned)(a.w!=SENTW);
          ok &= (unsigned)(b.x!=SENTW) & (unsigned)(b.y!=SENTW);
          ok &= (unsigned)(b.z!=SENTW) & (unsigned)(b.w!=SENTW);
          if (ok) break;
        }
        float* hb = hsh[t & 1];
        const int sb = (tid>>3)*68 + (tid&7)*8;
        hb[sb+0]=__uint_as_float(a.x); hb[sb+1]=__uint_as_float(a.y);
        hb[sb+2]=__uint_as_float(a.z); hb[sb+3]=__uint_as_float(a.w);
        hb[sb+4]=__uint_as_float(b.x); hb[sb+5]=__uint_as_float(b.y);
        hb[sb+6]=__uint_as_float(b.z); hb[sb+7]=__uint_as_float(b.w);
      }
      __syncthreads();

      const float* hv = hsh[t & 1] + kc*68;
      float p0=0.f,p1=0.f,p2=0.f,p3=0.f;
      #pragma unroll
      for (int j=0;j<16;j++){
        float4 q = *(const float4*)(hv + 4*j);
        p0 = fmaf(wreg[4*j+0], q.x, p0);
        p1 = fmaf(wreg[4*j+1], q.y, p1);
        p2 = fmaf(wreg[4*j+2], q.z, p2);
        p3 = fmaf(wreg[4*j+3], q.w, p3);
      }
      accv = (p0+p1)+(p2+p3);
      accv += __shfl_xor(accv, 1);
      accv += __shfl_xor(accv, 2);
      accv += __shfl_xor(accv, 4);
    }
    float act = 0.f;
    if (kc==0){
      float g = accv + preval;
      act = (gate==2) ? tanh_fast(g) : sigf(g);
    }
    float ai = __shfl(act, base+0);
    float af = __shfl(act, base+8);
    float ag = __shfl(act, base+16);
    float ao = __shfl(act, base+24);
    float h = 0.f;
    if ((tid&31)==0){
      c = af*c + ai*ag;
      h = ao*tanh_fast(c);
    }
    float h2 = __shfl(h, 32);
    if ((tid&63)==0){
      unsigned long long pv =
          ((unsigned long long)__float_as_uint(h2) << 32) | __float_as_uint(h);
      unsigned long long* dst =
          (unsigned long long*)(ob + (size_t)s*1024 + dir*512) + (w*8 + (tid>>6));
      (void)__hip_atomic_exchange(dst, pv, __ATOMIC_RELAXED, __HIP_MEMORY_SCOPE_AGENT);
    }
  }
}

// ---------------- row softmax, in place ----------------
__global__ __launch_bounds__(256) void k_softmax(float* __restrict__ P){
  __shared__ float redm[4], reds[4];
  const int i = blockIdx.x, tid = threadIdx.x;
  float4 v = *(float4*)&P[(size_t)i*1024 + tid*4];
  float m = fmaxf(fmaxf(v.x,v.y), fmaxf(v.z,v.w));
  #pragma unroll
  for (int o=32;o;o>>=1) m = fmaxf(m, __shfl_xor(m,o));
  if ((tid&63)==0) redm[tid>>6] = m;
  __syncthreads();
  m = fmaxf(fmaxf(redm[0],redm[1]), fmaxf(redm[2],redm[3]));
  v.x = expf(v.x-m); v.y = expf(v.y-m); v.z = expf(v.z-m); v.w = expf(v.w-m);
  float su = v.x+v.y+v.z+v.w;
  #pragma unroll
  for (int o=32;o;o>>=1) su += __shfl_xor(su,o);
  if ((tid&63)==0) reds[tid>>6] = su;
  __syncthreads();
  su = reds[0]+reds[1]+reds[2]+reds[3];
  float inv = 1.f/su;
  v.x*=inv; v.y*=inv; v.z*=inv; v.w*=inv;
  *(float4*)&P[(size_t)i*1024 + tid*4] = v;
}

extern "C" void kernel_launch(void* const* d_in, const int* in_sizes, int n_in,
                              void* d_out, int out_size, void* d_ws, size_t ws_size,
                              hipStream_t stream)
{
  const int*   x    = (const int*)d_in[0];
  const int*   xp   = (const int*)d_in[1];
  const float* we   = (const float*)d_in[2];
  const float* pe   = (const float*)d_in[3];
  const float* Wih  = (const float*)d_in[4];
  const float* Whh  = (const float*)d_in[5];
  const float* bl   = (const float*)d_in[6];
  const float* Wh   = (const float*)d_in[7];
  const float* bh   = (const float*)d_in[8];
  const float* Wd   = (const float*)d_in[9];
  const float* bd   = (const float*)d_in[10];
  const float* Wbi  = (const float*)d_in[11];
  const float* bbi  = (const float*)d_in[12];
  float* outp = (float*)d_out;

  char* ws = (char*)d_ws;
  float* pre  = (float*)(ws + ((size_t)4<<20)); // [4M,20M)
  float* out0 = (float*)(ws + ((size_t)20<<20));// [20M,24M)
  float* out1 = (float*)(ws + ((size_t)24<<20));// [24M,28M)
  float* head = (float*)(ws);                   // [0,4M)
  float* dep  = (float*)(ws + ((size_t)8<<20)); // [8M,12M)  (pre dead after scans? no - pre reused; keep dep separate)
  float* Ubuf = (float*)(ws + ((size_t)12<<20));// [12M,16M)

  // sentinel-init out0+out1 (data-as-flag for both scans)
  hipMemsetAsync(out0, 0x7F, (size_t)8<<20, stream);

  dim3 blk(256);

  // layer 0: pre = concat(we[x],pe[xp]) * Wih[0]^T + b[0]   (embed fused)
  k_gemm_emb<<<dim3(32,8), blk, 0, stream>>>(x, xp, we, pe, Wih, pre, bl);
  k_lstm_scan<<<64, dim3(512), 0, stream>>>(pre, Whh, out0);

  // layer 1
  k_gemm_abT<<<dim3(32,8), blk, 0, stream>>>(out0, Wih + (size_t)4096*1024, pre,
                                             1024, 4096, 1024, bl + 4096, nullptr);
  k_lstm_scan<<<64, dim3(512), 0, stream>>>(pre, Whh + (size_t)2*2048*512, out1);

  // biaffine: head|dep merged; U = dep*Wbi^T ; scores = head*U^T + bbi
  k_gemm_hd <<<dim3(16,8), blk, 0, stream>>>(out1, Wh, bh, head, Wd, bd, dep);
  k_gemm_abT<<<dim3(8,8), blk, 0, stream>>>(dep,  Wbi, Ubuf, 1024, 1024, 1024, nullptr, nullptr);
  k_gemm_abT<<<dim3(8,8), blk, 0, stream>>>(head, Ubuf, outp, 1024, 1024, 1024, nullptr, bbi);

  k_softmax<<<1024, blk, 0, stream>>>(outp);
}

// Round 13
// 4896.813 us; speedup vs baseline: 15.4864x; 1.3726x over previous
//
#include <hip/hip_runtime.h>
#include <hip/hip_bf16.h>
#include <cstdint>

#define SENTW 0x7F7F7F7Fu   // float ~3.39e38; never produced by h, pre, or GEMM outputs
typedef unsigned uint4v __attribute__((ext_vector_type(4)));

// fast activations: v_exp_f32 (2^x) + v_rcp_f32, ~1-2 ulp each
__device__ __forceinline__ float fexp(float x){
  return __builtin_amdgcn_exp2f(x * 1.44269504088896341f);
}
__device__ __forceinline__ float sigf(float x){
  return __builtin_amdgcn_rcpf(1.f + fexp(-x));
}
__device__ __forceinline__ float tanh_fast(float x){
  return 1.f - 2.f*__builtin_amdgcn_rcpf(fexp(2.f*x) + 1.f);
}

// coherent (LLC) loads/stores, bypass L1/L2 (the only cross-XCD-visible path, R5/R10-proven)
__device__ __forceinline__ unsigned ld_coh_u32(const unsigned* p){
  unsigned v;
  asm volatile("global_load_dword %0, %1, off sc0 sc1\n\ts_waitcnt vmcnt(0)"
               : "=v"(v) : "v"(p) : "memory");
  return v;
}
__device__ __forceinline__ uint4v ld_coh_u4(const float* p){
  uint4v v;
  asm volatile("global_load_dwordx4 %0, %1, off sc0 sc1\n\ts_waitcnt vmcnt(0)"
               : "=v"(v) : "v"(p) : "memory");
  return v;
}
// validated load: spin until no lane of the float4 equals the sentinel
__device__ __forceinline__ float4 ld_val_f4(const float* p){
  for(;;){
    uint4v v = ld_coh_u4(p);
    if (v.x!=SENTW && v.y!=SENTW && v.z!=SENTW && v.w!=SENTW){
      float4 f;
      f.x=__uint_as_float(v.x); f.y=__uint_as_float(v.y);
      f.z=__uint_as_float(v.z); f.w=__uint_as_float(v.w);
      return f;
    }
    __builtin_amdgcn_s_sleep(1);
  }
}
__device__ __forceinline__ void st_coh_f4(float* p, float4 f){
  uint4v v;
  v.x=__float_as_uint(f.x); v.y=__float_as_uint(f.y);
  v.z=__float_as_uint(f.z); v.w=__float_as_uint(f.w);
  asm volatile("global_store_dwordx4 %0, %1, off sc0 sc1" :: "v"(p), "v"(v) : "memory");
}

// ================= scan role (R7 measurement winner + validated preval) ======
__device__ void scan_role(
    const float* __restrict__ pre, const float* __restrict__ Whh,
    float* __restrict__ out, int vpre)
{
  const int wg  = blockIdx.x;
  const int dir = wg >> 5;
  const int w   = wg & 31;
  const int tid = threadIdx.x;
  const int kc  = tid & 7;
  const int rl  = tid >> 3;
  const int gate= rl & 3;
  const int ul  = rl >> 2;
  const int unit= w*16 + ul;
  const int grow= gate*512 + unit;

  __shared__ float hsh[2][544];

  float wreg[64];
  {
    const float* wp = Whh + ((size_t)dir*2048 + grow)*512 + kc*64;
    #pragma unroll
    for (int j=0;j<16;j++){
      float4 q = *(const float4*)(wp + 4*j);
      wreg[4*j+0]=q.x; wreg[4*j+1]=q.y; wreg[4*j+2]=q.z; wreg[4*j+3]=q.w;
    }
  }

  unsigned* ob = (unsigned*)out;
  const float* prebase = pre + (size_t)dir*2048 + grow;
  float c = 0.f;
  const int base = (tid & 32);

  for (int t=0;t<1024;t++){
    const int s  = dir ? (1023 - t) : t;
    const int sp = dir ? (s + 1) : (s - 1);

    const unsigned* pp = (const unsigned*)(prebase + (size_t)s*4096);
    unsigned pvbits = SENTW;
    float preval = 0.f;
    if (kc==0){
      if (vpre){ // issue coherent load WITHOUT waitcnt; poll's vmcnt(0) drains it
        asm volatile("global_load_dword %0, %1, off sc0 sc1"
                     : "=v"(pvbits) : "v"(pp) : "memory");
      } else {
        preval = prebase[(size_t)s*4096];
      }
    }

    float accv = 0.f;
    if (t > 0){
      if (tid < 64){
        const unsigned* hp = ob + (size_t)sp*1024 + dir*512 + 8*tid;
        uint4v a, b;
        for(;;){
          asm volatile(
            "global_load_dwordx4 %0, %2, off sc0 sc1\n\t"
            "global_load_dwordx4 %1, %3, off sc0 sc1\n\t"
            "s_waitcnt vmcnt(0)"
            : "=&v"(a), "=&v"(b)
            : "v"(hp), "v"(hp+4)
            : "memory");
          unsigned ok = 1u;
          ok &= (unsigned)(a.x!=SENTW) & (unsigned)(a.y!=SENTW);
          ok &= (unsigned)(a.z!=SENTW) & (unsigned)(a.w!=SENTW);
          ok &= (unsigned)(b.x!=SENTW) & (unsigned)(b.y!=SENTW);
          ok &= (unsigned)(b.z!=SENTW) & (unsigned)(b.w!=SENTW);
          if (ok) break;
        }
        float* hb = hsh[t & 1];
        const int sb = (tid>>3)*68 + (tid&7)*8;
        hb[sb+0]=__uint_as_float(a.x); hb[sb+1]=__uint_as_float(a.y);
        hb[sb+2]=__uint_as_float(a.z); hb[sb+3]=__uint_as_float(a.w);
        hb[sb+4]=__uint_as_float(b.x); hb[sb+5]=__uint_as_float(b.y);
        hb[sb+6]=__uint_as_float(b.z); hb[sb+7]=__uint_as_float(b.w);
      }
      __syncthreads();

      const float* hv = hsh[t & 1] + kc*68;
      float p0=0.f,p1=0.f,p2=0.f,p3=0.f;
      #pragma unroll
      for (int j=0;j<16;j++){
        float4 q = *(const float4*)(hv + 4*j);
        p0 = fmaf(wreg[4*j+0], q.x, p0);
        p1 = fmaf(wreg[4*j+1], q.y, p1);
        p2 = fmaf(wreg[4*j+2], q.z, p2);
        p3 = fmaf(wreg[4*j+3], q.w, p3);
      }
      accv = (p0+p1)+(p2+p3);
      accv += __shfl_xor(accv, 1);
      accv += __shfl_xor(accv, 2);
      accv += __shfl_xor(accv, 4);
    }
    if (vpre){
      asm volatile("s_waitcnt vmcnt(0)" ::: "memory");  // preval load drained
      if (kc==0){
        while (pvbits == SENTW){
          __builtin_amdgcn_s_sleep(1);
          pvbits = ld_coh_u32(pp);
        }
        preval = __uint_as_float(pvbits);
      }
    }
    float act = 0.f;
    if (kc==0){
      float g = accv + preval;
      act = (gate==2) ? tanh_fast(g) : sigf(g);
    }
    float ai = __shfl(act, base+0);
    float af = __shfl(act, base+8);
    float ag = __shfl(act, base+16);
    float ao = __shfl(act, base+24);
    float h = 0.f;
    if ((tid&31)==0){
      c = af*c + ai*ag;
      h = ao*tanh_fast(c);
    }
    float h2 = __shfl(h, 32);
    if ((tid&63)==0){
      unsigned long long pv =
          ((unsigned long long)__float_as_uint(h2) << 32) | __float_as_uint(h);
      unsigned long long* dst =
          (unsigned long long*)(ob + (size_t)s*1024 + dir*512) + (w*8 + (tid>>6));
      (void)__hip_atomic_exchange(dst, pv, __ATOMIC_RELAXED, __HIP_MEMORY_SCOPE_AGENT);
    }
  }
}

// ================= GEMM worker role (512 thr; tid<256 compute, barriers uniform)
// mode 0: A = gathered embeddings (we/pe), C stored COHERENT (same-kernel consumer)
// mode 1: A = scan output (sentinel-validated coherent loads), gated on row block;
//         C stored plain (next-kernel consumer). K=1024 fixed, 128x128 tile.
__device__ void worker_gemm(
    int mode,
    const int* __restrict__ x, const int* __restrict__ xp,
    const float* __restrict__ we, const float* __restrict__ pe,
    const float* __restrict__ A,
    const float* __restrict__ B, float* __restrict__ C, int N,
    const float* __restrict__ bias,
    const unsigned* __restrict__ gbuf, int m0, int n0)
{
  __shared__ float As[16][132];
  __shared__ float Bs[16][132];
  const int tid = threadIdx.x;

  // coarse gate: wait until out rows [m0, m0+127] are published (64 cells:
  // fwd-late row m0+127 cols 16w; bwd-late row m0 cols 512+16w), throttled.
  if (mode==1 && tid < 64){
    const unsigned* cell = (tid < 32)
      ? gbuf + (size_t)(m0+127)*1024 + 16*tid
      : gbuf + (size_t)m0*1024 + 512 + 16*(tid-32);
    while (ld_coh_u32(cell) == SENTW) __builtin_amdgcn_s_sleep(32);
  }
  __syncthreads();

  const bool active = tid < 256;
  const int r  = (tid>>1) & 127, cq = tid & 1;
  const int ty = (tid>>4) & 15,  tx = tid & 15;

  float acc[8][8];
  #pragma unroll
  for (int i=0;i<8;i++)
    #pragma unroll
    for (int j=0;j<8;j++) acc[i][j]=0.f;

  const float* bw  = nullptr;
  const float* bpo = nullptr;
  const float* ap  = nullptr;
  const float* bp  = nullptr;
  float4 a0, a1, b0, b1;
  if (active){
    if (mode==0){
      bw  = we + (size_t)x[m0+r]*896;
      bpo = pe + (size_t)xp[m0+r]*128 - 896;
    } else {
      ap = A + (size_t)(m0+r)*1024;
    }
    bp = B + (size_t)(n0+r)*1024 + cq*8;
    int kk = cq*8;
    if (mode==0){
      const float* src = (kk < 896 ? bw : bpo) + kk;
      a0 = *(const float4*)(src); a1 = *(const float4*)(src+4);
    } else {
      a0 = ld_val_f4(ap+kk); a1 = ld_val_f4(ap+kk+4);
    }
    b0 = *(const float4*)(bp); b1 = *(const float4*)(bp+4);
  }

  for (int k0=0;k0<1024;k0+=16){
    __syncthreads();
    if (active){
      As[cq*8+0][r]=a0.x; As[cq*8+1][r]=a0.y; As[cq*8+2][r]=a0.z; As[cq*8+3][r]=a0.w;
      As[cq*8+4][r]=a1.x; As[cq*8+5][r]=a1.y; As[cq*8+6][r]=a1.z; As[cq*8+7][r]=a1.w;
      Bs[cq*8+0][r]=b0.x; Bs[cq*8+1][r]=b0.y; Bs[cq*8+2][r]=b0.z; Bs[cq*8+3][r]=b0.w;
      Bs[cq*8+4][r]=b1.x; Bs[cq*8+5][r]=b1.y; Bs[cq*8+6][r]=b1.z; Bs[cq*8+7][r]=b1.w;
    }
    __syncthreads();
    if (active){
      if (k0+16 < 1024){
        int kk = k0+16+cq*8;
        if (mode==0){
          const float* src = (kk < 896 ? bw : bpo) + kk;
          a0 = *(const float4*)(src); a1 = *(const float4*)(src+4);
        } else {
          a0 = ld_val_f4(ap+kk); a1 = ld_val_f4(ap+kk+4);
        }
        b0 = *(const float4*)(bp+k0+16); b1 = *(const float4*)(bp+k0+20);
      }
      #pragma unroll
      for (int k=0;k<16;k++){
        float4 av0 = *(const float4*)&As[k][ty*8];
        float4 av1 = *(const float4*)&As[k][ty*8+4];
        float4 bv0 = *(const float4*)&Bs[k][tx*8];
        float4 bv1 = *(const float4*)&Bs[k][tx*8+4];
        float a[8]={av0.x,av0.y,av0.z,av0.w,av1.x,av1.y,av1.z,av1.w};
        float b[8]={bv0.x,bv0.y,bv0.z,bv0.w,bv1.x,bv1.y,bv1.z,bv1.w};
        #pragma unroll
        for (int i=0;i<8;i++)
          #pragma unroll
          for (int j=0;j<8;j++)
            acc[i][j] = fmaf(a[i],b[j],acc[i][j]);
      }
    }
  }

  if (active){
    float4 t0 = *(const float4*)&bias[n0+tx*8];
    float4 t1 = *(const float4*)&bias[n0+tx*8+4];
    float bv[8] = {t0.x,t0.y,t0.z,t0.w,t1.x,t1.y,t1.z,t1.w};
    #pragma unroll
    for (int i=0;i<8;i++){
      float* cp = C + (size_t)(m0+ty*8+i)*N + n0+tx*8;
      float4 o0, o1;
      o0.x=acc[i][0]+bv[0]; o0.y=acc[i][1]+bv[1];
      o0.z=acc[i][2]+bv[2]; o0.w=acc[i][3]+bv[3];
      o1.x=acc[i][4]+bv[4]; o1.y=acc[i][5]+bv[5];
      o1.z=acc[i][6]+bv[6]; o1.w=acc[i][7]+bv[7];
      if (mode==0){ st_coh_f4(cp, o0); st_coh_f4(cp+4, o1); }
      else        { *(float4*)cp = o0; *(float4*)(cp+4) = o1; }
    }
  }
}

// ================= mega kernel: scan + overlapped GEMM workers ===============
// layer 0: blocks 0-63 scan0; 64-319 embed workers (pre0, ungated);
//          320-575 layer-1 pre workers (gated on out0, write pre IN PLACE:
//          a row block's out0 readiness implies its pre0 rows are dead).
// layer 1: blocks 0-63 scan1; 64-191 head/dep workers (gated on out1).
__global__ __launch_bounds__(512,1) void k_mega(
    int layer,
    const int* __restrict__ x, const int* __restrict__ xp,
    const float* __restrict__ we, const float* __restrict__ pe,
    const float* __restrict__ Wih, const float* __restrict__ Whh,
    const float* __restrict__ bl,
    const float* __restrict__ Wh, const float* __restrict__ bh,
    const float* __restrict__ Wd, const float* __restrict__ bd,
    float* __restrict__ pre, float* __restrict__ out0, float* __restrict__ out1,
    float* __restrict__ head, float* __restrict__ dep)
{
  const int bid = blockIdx.x;
  if (bid < 64){
    scan_role(pre, Whh + (size_t)layer*2*2048*512,
              layer ? out1 : out0, layer==0 ? 1 : 0);
    return;
  }
  if (layer == 0){
    if (bid < 320){
      const int widx = bid - 64;
      worker_gemm(0, x, xp, we, pe, nullptr,
                  Wih, pre, 4096, bl, nullptr,
                  (widx>>5)*128, (widx&31)*128);
    } else {
      const int widx = bid - 320;
      worker_gemm(1, nullptr, nullptr, nullptr, nullptr, out0,
                  Wih + (size_t)4096*1024, pre, 4096, bl + 4096,
                  (const unsigned*)out0, (widx>>5)*128, (widx&31)*128);
    }
  } else {
    const int widx = bid - 64;
    const int half = widx >> 6, rest = widx & 63;
    worker_gemm(1, nullptr, nullptr, nullptr, nullptr, out1,
                half ? Wd : Wh, half ? dep : head, 1024, half ? bd : bh,
                (const unsigned*)out1, (rest>>3)*128, (rest&7)*128);
  }
}

// ---------------- fp32 GEMM (serial tail: U, scores) ----------------
__global__ __launch_bounds__(256,2) void k_gemm_abT(
    const float* __restrict__ A, const float* __restrict__ B, float* __restrict__ C,
    int M, int N, int K,
    const float* __restrict__ bias, const float* __restrict__ cadd)
{
  __shared__ float As[16][132];
  __shared__ float Bs[16][132];
  const int tid = threadIdx.x;
  const int m0 = blockIdx.y*128, n0 = blockIdx.x*128;
  const int r  = tid>>1, cq = tid&1;
  const int ty = tid>>4, tx = tid&15;

  float acc[8][8];
  #pragma unroll
  for (int i=0;i<8;i++)
    #pragma unroll
    for (int j=0;j<8;j++) acc[i][j]=0.f;

  const float* ap = A + (size_t)(m0+r)*K + cq*8;
  const float* bp = B + (size_t)(n0+r)*K + cq*8;
  float4 a0 = *(const float4*)(ap);
  float4 a1 = *(const float4*)(ap+4);
  float4 b0 = *(const float4*)(bp);
  float4 b1 = *(const float4*)(bp+4);

  for (int k0=0;k0<K;k0+=16){
    __syncthreads();
    As[cq*8+0][r]=a0.x; As[cq*8+1][r]=a0.y; As[cq*8+2][r]=a0.z; As[cq*8+3][r]=a0.w;
    As[cq*8+4][r]=a1.x; As[cq*8+5][r]=a1.y; As[cq*8+6][r]=a1.z; As[cq*8+7][r]=a1.w;
    Bs[cq*8+0][r]=b0.x; Bs[cq*8+1][r]=b0.y; Bs[cq*8+2][r]=b0.z; Bs[cq*8+3][r]=b0.w;
    Bs[cq*8+4][r]=b1.x; Bs[cq*8+5][r]=b1.y; Bs[cq*8+6][r]=b1.z; Bs[cq*8+7][r]=b1.w;
    __syncthreads();
    if (k0+16 < K){
      a0 = *(const float4*)(ap+k0+16);
      a1 = *(const float4*)(ap+k0+20);
      b0 = *(const float4*)(bp+k0+16);
      b1 = *(const float4*)(bp+k0+20);
    }
    #pragma unroll
    for (int k=0;k<16;k++){
      float4 av0 = *(const float4*)&As[k][ty*8];
      float4 av1 = *(const float4*)&As[k][ty*8+4];
      float4 bv0 = *(const float4*)&Bs[k][tx*8];
      float4 bv1 = *(const float4*)&Bs[k][tx*8+4];
      float a[8]={av0.x,av0.y,av0.z,av0.w,av1.x,av1.y,av1.z,av1.w};
      float b[8]={bv0.x,bv0.y,bv0.z,bv0.w,bv1.x,bv1.y,bv1.z,bv1.w};
      #pragma unroll
      for (int i=0;i<8;i++)
        #pragma unroll
        for (int j=0;j<8;j++)
          acc[i][j] = fmaf(a[i],b[j],acc[i][j]);
    }
  }

  float cb = cadd ? *cadd : 0.f;
  float bv[8];
  if (bias){
    float4 t0 = *(const float4*)&bias[n0+tx*8];
    float4 t1 = *(const float4*)&bias[n0+tx*8+4];
    bv[0]=t0.x; bv[1]=t0.y; bv[2]=t0.z; bv[3]=t0.w;
    bv[4]=t1.x; bv[5]=t1.y; bv[6]=t1.z; bv[7]=t1.w;
  } else {
    #pragma unroll
    for (int j=0;j<8;j++) bv[j]=0.f;
  }
  #pragma unroll
  for (int i=0;i<8;i++){
    float* cp = C + (size_t)(m0+ty*8+i)*N + n0+tx*8;
    float4 o0, o1;
    o0.x=acc[i][0]+bv[0]+cb; o0.y=acc[i][1]+bv[1]+cb;
    o0.z=acc[i][2]+bv[2]+cb; o0.w=acc[i][3]+bv[3]+cb;
    o1.x=acc[i][4]+bv[4]+cb; o1.y=acc[i][5]+bv[5]+cb;
    o1.z=acc[i][6]+bv[6]+cb; o1.w=acc[i][7]+bv[7]+cb;
    *(float4*)cp = o0; *(float4*)(cp+4) = o1;
  }
}

// ---------------- row softmax, in place ----------------
__global__ __launch_bounds__(256) void k_softmax(float* __restrict__ P){
  __shared__ float redm[4], reds[4];
  const int i = blockIdx.x, tid = threadIdx.x;
  float4 v = *(float4*)&P[(size_t)i*1024 + tid*4];
  float m = fmaxf(fmaxf(v.x,v.y), fmaxf(v.z,v.w));
  #pragma unroll
  for (int o=32;o;o>>=1) m = fmaxf(m, __shfl_xor(m,o));
  if ((tid&63)==0) redm[tid>>6] = m;
  __syncthreads();
  m = fmaxf(fmaxf(redm[0],redm[1]), fmaxf(redm[2],redm[3]));
  v.x = expf(v.x-m); v.y = expf(v.y-m); v.z = expf(v.z-m); v.w = expf(v.w-m);
  float su = v.x+v.y+v.z+v.w;
  #pragma unroll
  for (int o=32;o;o>>=1) su += __shfl_xor(su,o);
  if ((tid&63)==0) reds[tid>>6] = su;
  __syncthreads();
  su = reds[0]+reds[1]+reds[2]+reds[3];
  float inv = 1.f/su;
  v.x*=inv; v.y*=inv; v.z*=inv; v.w*=inv;
  *(float4*)&P[(size_t)i*1024 + tid*4] = v;
}

extern "C" void kernel_launch(void* const* d_in, const int* in_sizes, int n_in,
                              void* d_out, int out_size, void* d_ws, size_t ws_size,
                              hipStream_t stream)
{
  const int*   x    = (const int*)d_in[0];
  const int*   xp   = (const int*)d_in[1];
  const float* we   = (const float*)d_in[2];
  const float* pe   = (const float*)d_in[3];
  const float* Wih  = (const float*)d_in[4];
  const float* Whh  = (const float*)d_in[5];
  const float* bl   = (const float*)d_in[6];
  const float* Wh   = (const float*)d_in[7];
  const float* bh   = (const float*)d_in[8];
  const float* Wd   = (const float*)d_in[9];
  const float* bd   = (const float*)d_in[10];
  const float* Wbi  = (const float*)d_in[11];
  const float* bbi  = (const float*)d_in[12];
  float* outp = (float*)d_out;

  char* ws = (char*)d_ws;
  float* head = (float*)(ws);                    // [0,4M)
  float* pre  = (float*)(ws + ((size_t)4<<20));  // [4M,20M)  pre0 -> pre1 in place
  float* out0 = (float*)(ws + ((size_t)20<<20)); // [20M,24M) -> Ubuf after megaA
  float* out1 = (float*)(ws + ((size_t)24<<20)); // [24M,28M)
  float* Ubuf = out0;                            // out0 dead after megaA
  float* dep  = (float*)d_out;                   // d_out dead until scores GEMM

  dim3 blk(256);

  // sentinel-init: pre (scan0 preval validation) + out0/out1 (data-as-flag)
  hipMemsetAsync(pre,  0x7F, (size_t)16<<20, stream);
  hipMemsetAsync(out0, 0x7F, (size_t)8<<20,  stream);

  // megaA: scan0 + embed workers (pre0) + layer-1 pre workers (gated)
  k_mega<<<576, dim3(512), 0, stream>>>(0, x, xp, we, pe, Wih, Whh, bl,
                                        Wh, bh, Wd, bd, pre, out0, out1, head, dep);
  // megaB: scan1 + head/dep workers (gated on out1)
  k_mega<<<192, dim3(512), 0, stream>>>(1, x, xp, we, pe, Wih, Whh, bl,
                                        Wh, bh, Wd, bd, pre, out0, out1, head, dep);

  // serial tail: U = dep*Wbi^T ; scores = head*U^T + bbi ; softmax
  k_gemm_abT<<<dim3(8,8), blk, 0, stream>>>(dep,  Wbi,  Ubuf, 1024, 1024, 1024, nullptr, nullptr);
  k_gemm_abT<<<dim3(8,8), blk, 0, stream>>>(head, Ubuf, outp, 1024, 1024, 1024, nullptr, bbi);
  k_softmax<<<1024, blk, 0, stream>>>(outp);
}

// Round 19
// 4885.369 us; speedup vs baseline: 15.5226x; 1.0023x over previous
//
#include <hip/hip_runtime.h>
#include <hip/hip_bf16.h>
#include <cstdint>

#define SENTW 0x7F7F7F7Fu   // float ~3.39e38; never produced by h, pre, or GEMM outputs
typedef unsigned uint4v __attribute__((ext_vector_type(4)));

// fast activations: v_exp_f32 (2^x) + v_rcp_f32, ~1-2 ulp each
__device__ __forceinline__ float fexp(float x){
  return __builtin_amdgcn_exp2f(x * 1.44269504088896341f);
}
__device__ __forceinline__ float sigf(float x){
  return __builtin_amdgcn_rcpf(1.f + fexp(-x));
}
__device__ __forceinline__ float tanh_fast(float x){
  return 1.f - 2.f*__builtin_amdgcn_rcpf(fexp(2.f*x) + 1.f);
}

// coherent (LLC) loads/stores, bypass L1/L2 (the only cross-XCD-visible path, R5/R10-proven)
__device__ __forceinline__ unsigned ld_coh_u32(const unsigned* p){
  unsigned v;
  asm volatile("global_load_dword %0, %1, off sc0 sc1\n\ts_waitcnt vmcnt(0)"
               : "=v"(v) : "v"(p) : "memory");
  return v;
}
__device__ __forceinline__ uint4v ld_coh_u4(const float* p){
  uint4v v;
  asm volatile("global_load_dwordx4 %0, %1, off sc0 sc1\n\ts_waitcnt vmcnt(0)"
               : "=v"(v) : "v"(p) : "memory");
  return v;
}
// validated load: spin until no lane of the float4 equals the sentinel
__device__ __forceinline__ float4 ld_val_f4(const float* p){
  for(;;){
    uint4v v = ld_coh_u4(p);
    if (v.x!=SENTW && v.y!=SENTW && v.z!=SENTW && v.w!=SENTW){
      float4 f;
      f.x=__uint_as_float(v.x); f.y=__uint_as_float(v.y);
      f.z=__uint_as_float(v.z); f.w=__uint_as_float(v.w);
      return f;
    }
    __builtin_amdgcn_s_sleep(1);
  }
}
__device__ __forceinline__ void st_coh_f4(float* p, float4 f){
  uint4v v;
  v.x=__float_as_uint(f.x); v.y=__float_as_uint(f.y);
  v.z=__float_as_uint(f.z); v.w=__float_as_uint(f.w);
  asm volatile("global_store_dwordx4 %0, %1, off sc0 sc1" :: "v"(p), "v"(v) : "memory");
}

// ================= scan role (R7 measurement winner + validated preval) ======
__device__ void scan_role(
    const float* __restrict__ pre, const float* __restrict__ Whh,
    float* __restrict__ out, int vpre)
{
  const int wg  = blockIdx.x;
  const int dir = wg >> 5;
  const int w   = wg & 31;
  const int tid = threadIdx.x;
  const int kc  = tid & 7;
  const int rl  = tid >> 3;
  const int gate= rl & 3;
  const int ul  = rl >> 2;
  const int unit= w*16 + ul;
  const int grow= gate*512 + unit;

  __shared__ float hsh[2][544];

  float wreg[64];
  {
    const float* wp = Whh + ((size_t)dir*2048 + grow)*512 + kc*64;
    #pragma unroll
    for (int j=0;j<16;j++){
      float4 q = *(const float4*)(wp + 4*j);
      wreg[4*j+0]=q.x; wreg[4*j+1]=q.y; wreg[4*j+2]=q.z; wreg[4*j+3]=q.w;
    }
  }

  unsigned* ob = (unsigned*)out;
  const float* prebase = pre + (size_t)dir*2048 + grow;
  float c = 0.f;
  const int base = (tid & 32);

  for (int t=0;t<1024;t++){
    const int s  = dir ? (1023 - t) : t;
    const int sp = dir ? (s + 1) : (s - 1);

    const unsigned* pp = (const unsigned*)(prebase + (size_t)s*4096);
    unsigned pvbits = SENTW;
    float preval = 0.f;
    if (kc==0){
      if (vpre){ // issue coherent load WITHOUT waitcnt; poll's vmcnt(0) drains it
        asm volatile("global_load_dword %0, %1, off sc0 sc1"
                     : "=v"(pvbits) : "v"(pp) : "memory");
      } else {
        preval = prebase[(size_t)s*4096];
      }
    }

    float accv = 0.f;
    if (t > 0){
      if (tid < 64){
        const unsigned* hp = ob + (size_t)sp*1024 + dir*512 + 8*tid;
        uint4v a, b;
        for(;;){
          asm volatile(
            "global_load_dwordx4 %0, %2, off sc0 sc1\n\t"
            "global_load_dwordx4 %1, %3, off sc0 sc1\n\t"
            "s_waitcnt vmcnt(0)"
            : "=&v"(a), "=&v"(b)
            : "v"(hp), "v"(hp+4)
            : "memory");
          unsigned ok = 1u;
          ok &= (unsigned)(a.x!=SENTW) & (unsigned)(a.y!=SENTW);
          ok &= (unsigned)(a.z!=SENTW) & (unsigned)(a.w!=SENTW);
          ok &= (unsigned)(b.x!=SENTW) & (unsigned)(b.y!=SENTW);
          ok &= (unsigned)(b.z!=SENTW) & (unsigned)(b.w!=SENTW);
          if (ok) break;
        }
        float* hb = hsh[t & 1];
        const int sb = (tid>>3)*68 + (tid&7)*8;
        hb[sb+0]=__uint_as_float(a.x); hb[sb+1]=__uint_as_float(a.y);
        hb[sb+2]=__uint_as_float(a.z); hb[sb+3]=__uint_as_float(a.w);
        hb[sb+4]=__uint_as_float(b.x); hb[sb+5]=__uint_as_float(b.y);
        hb[sb+6]=__uint_as_float(b.z); hb[sb+7]=__uint_as_float(b.w);
      }
      __syncthreads();

      const float* hv = hsh[t & 1] + kc*68;
      float p0=0.f,p1=0.f,p2=0.f,p3=0.f;
      #pragma unroll
      for (int j=0;j<16;j++){
        float4 q = *(const float4*)(hv + 4*j);
        p0 = fmaf(wreg[4*j+0], q.x, p0);
        p1 = fmaf(wreg[4*j+1], q.y, p1);
        p2 = fmaf(wreg[4*j+2], q.z, p2);
        p3 = fmaf(wreg[4*j+3], q.w, p3);
      }
      accv = (p0+p1)+(p2+p3);
      accv += __shfl_xor(accv, 1);
      accv += __shfl_xor(accv, 2);
      accv += __shfl_xor(accv, 4);
    }
    if (vpre){
      asm volatile("s_waitcnt vmcnt(0)" ::: "memory");  // preval load drained
      if (kc==0){
        while (pvbits == SENTW){
          __builtin_amdgcn_s_sleep(1);
          pvbits = ld_coh_u32(pp);
        }
        preval = __uint_as_float(pvbits);
      }
    }
    float act = 0.f;
    if (kc==0){
      float g = accv + preval;
      act = (gate==2) ? tanh_fast(g) : sigf(g);
    }
    float ai = __shfl(act, base+0);
    float af = __shfl(act, base+8);
    float ag = __shfl(act, base+16);
    float ao = __shfl(act, base+24);
    float h = 0.f;
    if ((tid&31)==0){
      c = af*c + ai*ag;
      h = ao*tanh_fast(c);
    }
    float h2 = __shfl(h, 32);
    if ((tid&63)==0){
      unsigned long long pv =
          ((unsigned long long)__float_as_uint(h2) << 32) | __float_as_uint(h);
      unsigned long long* dst =
          (unsigned long long*)(ob + (size_t)s*1024 + dir*512) + (w*8 + (tid>>6));
      (void)__hip_atomic_exchange(dst, pv, __ATOMIC_RELAXED, __HIP_MEMORY_SCOPE_AGENT);
    }
  }
}

// ================= GEMM worker role (512 thr; tid<256 compute, barriers uniform)
// mode 0: A = gathered embeddings (we/pe), C stored COHERENT (same-kernel consumer)
// mode 1: A = scan output (sentinel-validated coherent loads), gated on row block;
//         C stored plain (next-kernel consumer). K=1024 fixed, 128x128 tile.
__device__ void worker_gemm(
    int mode,
    const int* __restrict__ x, const int* __restrict__ xp,
    const float* __restrict__ we, const float* __restrict__ pe,
    const float* __restrict__ A,
    const float* __restrict__ B, float* __restrict__ C, int N,
    const float* __restrict__ bias,
    const unsigned* __restrict__ gbuf, int m0, int n0)
{
  __shared__ float As[16][132];
  __shared__ float Bs[16][132];
  const int tid = threadIdx.x;

  // coarse gate: wait until out rows [m0, m0+127] are published (64 cells:
  // fwd-late row m0+127 cols 16w; bwd-late row m0 cols 512+16w), throttled.
  if (mode==1 && tid < 64){
    const unsigned* cell = (tid < 32)
      ? gbuf + (size_t)(m0+127)*1024 + 16*tid
      : gbuf + (size_t)m0*1024 + 512 + 16*(tid-32);
    while (ld_coh_u32(cell) == SENTW) __builtin_amdgcn_s_sleep(32);
  }
  __syncthreads();

  const bool active = tid < 256;
  const int r  = (tid>>1) & 127, cq = tid & 1;
  const int ty = (tid>>4) & 15,  tx = tid & 15;

  float acc[8][8];
  #pragma unroll
  for (int i=0;i<8;i++)
    #pragma unroll
    for (int j=0;j<8;j++) acc[i][j]=0.f;

  const float* bw  = nullptr;
  const float* bpo = nullptr;
  const float* ap  = nullptr;
  const float* bp  = nullptr;
  float4 a0, a1, b0, b1;
  if (active){
    if (mode==0){
      bw  = we + (size_t)x[m0+r]*896;
      bpo = pe + (size_t)xp[m0+r]*128 - 896;
    } else {
      ap = A + (size_t)(m0+r)*1024;
    }
    bp = B + (size_t)(n0+r)*1024 + cq*8;
    int kk = cq*8;
    if (mode==0){
      const float* src = (kk < 896 ? bw : bpo) + kk;
      a0 = *(const float4*)(src); a1 = *(const float4*)(src+4);
    } else {
      a0 = ld_val_f4(ap+kk); a1 = ld_val_f4(ap+kk+4);
    }
    b0 = *(const float4*)(bp); b1 = *(const float4*)(bp+4);
  }

  for (int k0=0;k0<1024;k0+=16){
    __syncthreads();
    if (active){
      As[cq*8+0][r]=a0.x; As[cq*8+1][r]=a0.y; As[cq*8+2][r]=a0.z; As[cq*8+3][r]=a0.w;
      As[cq*8+4][r]=a1.x; As[cq*8+5][r]=a1.y; As[cq*8+6][r]=a1.z; As[cq*8+7][r]=a1.w;
      Bs[cq*8+0][r]=b0.x; Bs[cq*8+1][r]=b0.y; Bs[cq*8+2][r]=b0.z; Bs[cq*8+3][r]=b0.w;
      Bs[cq*8+4][r]=b1.x; Bs[cq*8+5][r]=b1.y; Bs[cq*8+6][r]=b1.z; Bs[cq*8+7][r]=b1.w;
    }
    __syncthreads();
    if (active){
      if (k0+16 < 1024){
        int kk = k0+16+cq*8;
        if (mode==0){
          const float* src = (kk < 896 ? bw : bpo) + kk;
          a0 = *(const float4*)(src); a1 = *(const float4*)(src+4);
        } else {
          a0 = ld_val_f4(ap+kk); a1 = ld_val_f4(ap+kk+4);
        }
        b0 = *(const float4*)(bp+k0+16); b1 = *(const float4*)(bp+k0+20);
      }
      #pragma unroll
      for (int k=0;k<16;k++){
        float4 av0 = *(const float4*)&As[k][ty*8];
        float4 av1 = *(const float4*)&As[k][ty*8+4];
        float4 bv0 = *(const float4*)&Bs[k][tx*8];
        float4 bv1 = *(const float4*)&Bs[k][tx*8+4];
        float a[8]={av0.x,av0.y,av0.z,av0.w,av1.x,av1.y,av1.z,av1.w};
        float b[8]={bv0.x,bv0.y,bv0.z,bv0.w,bv1.x,bv1.y,bv1.z,bv1.w};
        #pragma unroll
        for (int i=0;i<8;i++)
          #pragma unroll
          for (int j=0;j<8;j++)
            acc[i][j] = fmaf(a[i],b[j],acc[i][j]);
      }
    }
  }

  if (active){
    float4 t0 = *(const float4*)&bias[n0+tx*8];
    float4 t1 = *(const float4*)&bias[n0+tx*8+4];
    float bv[8] = {t0.x,t0.y,t0.z,t0.w,t1.x,t1.y,t1.z,t1.w};
    #pragma unroll
    for (int i=0;i<8;i++){
      float* cp = C + (size_t)(m0+ty*8+i)*N + n0+tx*8;
      float4 o0, o1;
      o0.x=acc[i][0]+bv[0]; o0.y=acc[i][1]+bv[1];
      o0.z=acc[i][2]+bv[2]; o0.w=acc[i][3]+bv[3];
      o1.x=acc[i][4]+bv[4]; o1.y=acc[i][5]+bv[5];
      o1.z=acc[i][6]+bv[6]; o1.w=acc[i][7]+bv[7];
      if (mode==0){ st_coh_f4(cp, o0); st_coh_f4(cp+4, o1); }
      else        { *(float4*)cp = o0; *(float4*)(cp+4) = o1; }
    }
  }
}

// ================= mega kernel: scan + overlapped GEMM workers ===============
// layer 0: blocks 0-63 scan0; 64-319 embed workers (pre0, ungated);
//          320-575 layer-1 pre workers (gated on out0, write pre IN PLACE:
//          a row block's out0 readiness implies its pre0 rows are dead).
// layer 1: blocks 0-63 scan1; 64-191 head/dep workers (gated on out1).
__global__ __launch_bounds__(512,1) void k_mega(
    int layer,
    const int* __restrict__ x, const int* __restrict__ xp,
    const float* __restrict__ we, const float* __restrict__ pe,
    const float* __restrict__ Wih, const float* __restrict__ Whh,
    const float* __restrict__ bl,
    const float* __restrict__ Wh, const float* __restrict__ bh,
    const float* __restrict__ Wd, const float* __restrict__ bd,
    float* __restrict__ pre, float* __restrict__ out0, float* __restrict__ out1,
    float* __restrict__ head, float* __restrict__ dep)
{
  const int bid = blockIdx.x;
  if (bid < 64){
    scan_role(pre, Whh + (size_t)layer*2*2048*512,
              layer ? out1 : out0, layer==0 ? 1 : 0);
    return;
  }
  if (layer == 0){
    if (bid < 320){
      const int widx = bid - 64;
      worker_gemm(0, x, xp, we, pe, nullptr,
                  Wih, pre, 4096, bl, nullptr,
                  (widx>>5)*128, (widx&31)*128);
    } else {
      const int widx = bid - 320;
      worker_gemm(1, nullptr, nullptr, nullptr, nullptr, out0,
                  Wih + (size_t)4096*1024, pre, 4096, bl + 4096,
                  (const unsigned*)out0, (widx>>5)*128, (widx&31)*128);
    }
  } else {
    const int widx = bid - 64;
    const int half = widx >> 6, rest = widx & 63;
    worker_gemm(1, nullptr, nullptr, nullptr, nullptr, out1,
                half ? Wd : Wh, half ? dep : head, 1024, half ? bd : bh,
                (const unsigned*)out1, (rest>>3)*128, (rest&7)*128);
  }
}

// ---------------- fp32 GEMM (serial tail: U, scores) ----------------
__global__ __launch_bounds__(256,2) void k_gemm_abT(
    const float* __restrict__ A, const float* __restrict__ B, float* __restrict__ C,
    int M, int N, int K,
    const float* __restrict__ bias, const float* __restrict__ cadd)
{
  __shared__ float As[16][132];
  __shared__ float Bs[16][132];
  const int tid = threadIdx.x;
  const int m0 = blockIdx.y*128, n0 = blockIdx.x*128;
  const int r  = tid>>1, cq = tid&1;
  const int ty = tid>>4, tx = tid&15;

  float acc[8][8];
  #pragma unroll
  for (int i=0;i<8;i++)
    #pragma unroll
    for (int j=0;j<8;j++) acc[i][j]=0.f;

  const float* ap = A + (size_t)(m0+r)*K + cq*8;
  const float* bp = B + (size_t)(n0+r)*K + cq*8;
  float4 a0 = *(const float4*)(ap);
  float4 a1 = *(const float4*)(ap+4);
  float4 b0 = *(const float4*)(bp);
  float4 b1 = *(const float4*)(bp+4);

  for (int k0=0;k0<K;k0+=16){
    __syncthreads();
    As[cq*8+0][r]=a0.x; As[cq*8+1][r]=a0.y; As[cq*8+2][r]=a0.z; As[cq*8+3][r]=a0.w;
    As[cq*8+4][r]=a1.x; As[cq*8+5][r]=a1.y; As[cq*8+6][r]=a1.z; As[cq*8+7][r]=a1.w;
    Bs[cq*8+0][r]=b0.x; Bs[cq*8+1][r]=b0.y; Bs[cq*8+2][r]=b0.z; Bs[cq*8+3][r]=b0.w;
    Bs[cq*8+4][r]=b1.x; Bs[cq*8+5][r]=b1.y; Bs[cq*8+6][r]=b1.z; Bs[cq*8+7][r]=b1.w;
    __syncthreads();
    if (k0+16 < K){
      a0 = *(const float4*)(ap+k0+16);
      a1 = *(const float4*)(ap+k0+20);
      b0 = *(const float4*)(bp+k0+16);
      b1 = *(const float4*)(bp+k0+20);
    }
    #pragma unroll
    for (int k=0;k<16;k++){
      float4 av0 = *(const float4*)&As[k][ty*8];
      float4 av1 = *(const float4*)&As[k][ty*8+4];
      float4 bv0 = *(const float4*)&Bs[k][tx*8];
      float4 bv1 = *(const float4*)&Bs[k][tx*8+4];
      float a[8]={av0.x,av0.y,av0.z,av0.w,av1.x,av1.y,av1.z,av1.w};
      float b[8]={bv0.x,bv0.y,bv0.z,bv0.w,bv1.x,bv1.y,bv1.z,bv1.w};
      #pragma unroll
      for (int i=0;i<8;i++)
        #pragma unroll
        for (int j=0;j<8;j++)
          acc[i][j] = fmaf(a[i],b[j],acc[i][j]);
    }
  }

  float cb = cadd ? *cadd : 0.f;
  float bv[8];
  if (bias){
    float4 t0 = *(const float4*)&bias[n0+tx*8];
    float4 t1 = *(const float4*)&bias[n0+tx*8+4];
    bv[0]=t0.x; bv[1]=t0.y; bv[2]=t0.z; bv[3]=t0.w;
    bv[4]=t1.x; bv[5]=t1.y; bv[6]=t1.z; bv[7]=t1.w;
  } else {
    #pragma unroll
    for (int j=0;j<8;j++) bv[j]=0.f;
  }
  #pragma unroll
  for (int i=0;i<8;i++){
    float* cp = C + (size_t)(m0+ty*8+i)*N + n0+tx*8;
    float4 o0, o1;
    o0.x=acc[i][0]+bv[0]+cb; o0.y=acc[i][1]+bv[1]+cb;
    o0.z=acc[i][2]+bv[2]+cb; o0.w=acc[i][3]+bv[3]+cb;
    o1.x=acc[i][4]+bv[4]+cb; o1.y=acc[i][5]+bv[5]+cb;
    o1.z=acc[i][6]+bv[6]+cb; o1.w=acc[i][7]+bv[7]+cb;
    *(float4*)cp = o0; *(float4*)(cp+4) = o1;
  }
}

// ---------------- row softmax, in place ----------------
__global__ __launch_bounds__(256) void k_softmax(float* __restrict__ P){
  __shared__ float redm[4], reds[4];
  const int i = blockIdx.x, tid = threadIdx.x;
  float4 v = *(float4*)&P[(size_t)i*1024 + tid*4];
  float m = fmaxf(fmaxf(v.x,v.y), fmaxf(v.z,v.w));
  #pragma unroll
  for (int o=32;o;o>>=1) m = fmaxf(m, __shfl_xor(m,o));
  if ((tid&63)==0) redm[tid>>6] = m;
  __syncthreads();
  m = fmaxf(fmaxf(redm[0],redm[1]), fmaxf(redm[2],redm[3]));
  v.x = expf(v.x-m); v.y = expf(v.y-m); v.z = expf(v.z-m); v.w = expf(v.w-m);
  float su = v.x+v.y+v.z+v.w;
  #pragma unroll
  for (int o=32;o;o>>=1) su += __shfl_xor(su,o);
  if ((tid&63)==0) reds[tid>>6] = su;
  __syncthreads();
  su = reds[0]+reds[1]+reds[2]+reds[3];
  float inv = 1.f/su;
  v.x*=inv; v.y*=inv; v.z*=inv; v.w*=inv;
  *(float4*)&P[(size_t)i*1024 + tid*4] = v;
}

extern "C" void kernel_launch(void* const* d_in, const int* in_sizes, int n_in,
                              void* d_out, int out_size, void* d_ws, size_t ws_size,
                              hipStream_t stream)
{
  const int*   x    = (const int*)d_in[0];
  const int*   xp   = (const int*)d_in[1];
  const float* we   = (const float*)d_in[2];
  const float* pe   = (const float*)d_in[3];
  const float* Wih  = (const float*)d_in[4];
  const float* Whh  = (const float*)d_in[5];
  const float* bl   = (const float*)d_in[6];
  const float* Wh   = (const float*)d_in[7];
  const float* bh   = (const float*)d_in[8];
  const float* Wd   = (const float*)d_in[9];
  const float* bd   = (const float*)d_in[10];
  const float* Wbi  = (const float*)d_in[11];
  const float* bbi  = (const float*)d_in[12];
  float* outp = (float*)d_out;

  char* ws = (char*)d_ws;
  float* head = (float*)(ws);                    // [0,4M)
  float* pre  = (float*)(ws + ((size_t)4<<20));  // [4M,20M)  pre0 -> pre1 in place
  float* out0 = (float*)(ws + ((size_t)20<<20)); // [20M,24M) -> Ubuf after megaA
  float* out1 = (float*)(ws + ((size_t)24<<20)); // [24M,28M)
  float* Ubuf = out0;                            // out0 dead after megaA
  float* dep  = (float*)d_out;                   // d_out dead until scores GEMM

  dim3 blk(256);

  // sentinel-init: pre (scan0 preval validation) + out0/out1 (data-as-flag)
  hipMemsetAsync(pre,  0x7F, (size_t)16<<20, stream);
  hipMemsetAsync(out0, 0x7F, (size_t)8<<20,  stream);

  // megaA: scan0 + embed workers (pre0) + layer-1 pre workers (gated)
  k_mega<<<576, dim3(512), 0, stream>>>(0, x, xp, we, pe, Wih, Whh, bl,
                                        Wh, bh, Wd, bd, pre, out0, out1, head, dep);
  // megaB: scan1 + head/dep workers (gated on out1)
  k_mega<<<192, dim3(512), 0, stream>>>(1, x, xp, we, pe, Wih, Whh, bl,
                                        Wh, bh, Wd, bd, pre, out0, out1, head, dep);

  // serial tail: U = dep*Wbi^T ; scores = head*U^T + bbi ; softmax
  k_gemm_abT<<<dim3(8,8), blk, 0, stream>>>(dep,  Wbi,  Ubuf, 1024, 1024, 1024, nullptr, nullptr);
  k_gemm_abT<<<dim3(8,8), blk, 0, stream>>>(head, Ubuf, outp, 1024, 1024, 1024, nullptr, bbi);
  k_softmax<<<1024, blk, 0, stream>>>(outp);
}